// Round 1
// baseline (227.936 us; speedup 1.0000x reference)
//
#include <hip/hip_runtime.h>

// ---------------- common types / helpers ----------------
using bf16x8 = __attribute__((ext_vector_type(8))) short;
using f32x4  = __attribute__((ext_vector_type(4))) float;

#define S_LEN 2048
#define NHEAD 16
#define DKH   64
#define HSZ   (S_LEN * DKH * 32)  // B*H*S*DK = 4194304 elems per matrix

__device__ __forceinline__ unsigned short f2bf(float x) {
  unsigned u = __builtin_bit_cast(unsigned, x);
  u += 0x7FFFu + ((u >> 16) & 1u);          // RNE
  return (unsigned short)(u >> 16);
}

__device__ __forceinline__ void gload_lds16(const void* g, void* l) {
  __builtin_amdgcn_global_load_lds(
      (const __attribute__((address_space(1))) unsigned int*)g,
      (__attribute__((address_space(3))) unsigned int*)l, 16, 0, 0);
}

// ---------------- fp32 -> bf16 conversion ----------------
__global__ void cvt_kernel(const float* __restrict__ src,
                           unsigned short* __restrict__ dst, int n4) {
  int i = blockIdx.x * blockDim.x + threadIdx.x;
  if (i < n4) {
    float4 v = ((const float4*)src)[i];
    ushort4 o;
    o.x = f2bf(v.x); o.y = f2bf(v.y); o.z = f2bf(v.z); o.w = f2bf(v.w);
    ((ushort4*)dst)[i] = o;
  }
}

// ---------------- prefix lengths ----------------
__global__ void lens_kernel(const int* __restrict__ mask, int* __restrict__ lens) {
  __shared__ int sred[256];
  const int b = blockIdx.x;
  int c = 0;
  for (int s = threadIdx.x; s < S_LEN; s += 256) c += (mask[b * S_LEN + s] != 0) ? 1 : 0;
  sred[threadIdx.x] = c;
  __syncthreads();
  for (int st = 128; st > 0; st >>= 1) {
    if (threadIdx.x < st) sred[threadIdx.x] += sred[threadIdx.x + st];
    __syncthreads();
  }
  if (threadIdx.x == 0) lens[b] = sred[0];
}

// ---------------- m97-style 128x128x32 bf16 GEMM ----------------
// C[m,n] = sum_k A[m,k]*B[n,k]  (A: MxK row-major, B: NxK row-major)
// MODE 0: QKV epilogue -> bf16 [3][B,H,S,DK], Q scaled by 0.125
// MODE 1: fp32 out[m*1024+n] + bias
template <int MODE>
__global__ __launch_bounds__(256) void gemm_kernel(
    const unsigned short* __restrict__ A, const unsigned short* __restrict__ B,
    const float* __restrict__ b0, const float* __restrict__ b1,
    const float* __restrict__ b2, unsigned short* __restrict__ outQKV,
    float* __restrict__ outF, const int K) {
  __shared__ __align__(16) unsigned short As[128 * 32];
  __shared__ __align__(16) unsigned short Bs[128 * 32];
  const int tid = threadIdx.x;
  const int w = tid >> 6, lane = tid & 63;
  const int wm = w >> 1, wn = w & 1;
  const int r = lane & 15, g = lane >> 4;
  const int tm = blockIdx.y * 128, tn = blockIdx.x * 128;

  f32x4 acc[4][4] = {};
  const char* Ab = (const char*)A;
  const char* Bb = (const char*)B;
  char* AsB = (char*)As;
  char* BsB = (char*)Bs;

  for (int k0 = 0; k0 < K; k0 += 32) {
#pragma unroll
    for (int i = 0; i < 2; ++i) {
      const int o = (w * 2 + i) * 1024 + lane * 16;  // byte offset in 8KB tile
      const int row = o >> 6, colb = o & 63;
      gload_lds16(Ab + ((size_t)(tm + row) * K + k0) * 2 + colb, AsB + (w * 2 + i) * 1024);
      gload_lds16(Bb + ((size_t)(tn + row) * K + k0) * 2 + colb, BsB + (w * 2 + i) * 1024);
    }
    __syncthreads();
    bf16x8 af[4], bfr[4];
#pragma unroll
    for (int mi = 0; mi < 4; ++mi)
      af[mi] = *(const bf16x8*)(AsB + (wm * 64 + mi * 16 + r) * 64 + g * 16);
#pragma unroll
    for (int ni = 0; ni < 4; ++ni)
      bfr[ni] = *(const bf16x8*)(BsB + (wn * 64 + ni * 16 + r) * 64 + g * 16);
#pragma unroll
    for (int mi = 0; mi < 4; ++mi)
#pragma unroll
      for (int ni = 0; ni < 4; ++ni)
        acc[mi][ni] = __builtin_amdgcn_mfma_f32_16x16x32_bf16(af[mi], bfr[ni], acc[mi][ni], 0, 0, 0);
    __syncthreads();
  }

  if (MODE == 0) {
    const int mat = tn >> 10;  // tile never straddles a 1024 boundary
    const float* bp = (mat == 0) ? b0 : (mat == 1) ? b1 : b2;
    const float scale = (mat == 0) ? 0.125f : 1.0f;
    unsigned short* dst = outQKV + (size_t)mat * HSZ;
#pragma unroll
    for (int mi = 0; mi < 4; ++mi)
#pragma unroll
      for (int ni = 0; ni < 4; ++ni)
#pragma unroll
        for (int reg = 0; reg < 4; ++reg) {
          const int m = tm + wm * 64 + mi * 16 + 4 * g + reg;
          const int n = tn + wn * 64 + ni * 16 + r;
          const int nn = n & 1023;
          const float v = (acc[mi][ni][reg] + bp[nn]) * scale;
          const int bI = m >> 11, s = m & 2047, hh = nn >> 6, dk = nn & 63;
          dst[(size_t)((bI * NHEAD + hh) * S_LEN + s) * DKH + dk] = f2bf(v);
        }
  } else {
#pragma unroll
    for (int mi = 0; mi < 4; ++mi)
#pragma unroll
      for (int ni = 0; ni < 4; ++ni)
#pragma unroll
        for (int reg = 0; reg < 4; ++reg) {
          const int m = tm + wm * 64 + mi * 16 + 4 * g + reg;
          const int n = tn + wn * 64 + ni * 16 + r;
          outF[(size_t)m * 1024 + n] = acc[mi][ni][reg] + b0[n];
        }
  }
}

// ---------------- flash attention ----------------
// grid (S/64, B*H); 4 waves x 16 q-rows. Swapped QK^T: lane owns one score row.
__global__ __launch_bounds__(256) void attn_kernel(
    const unsigned short* __restrict__ qkv, const int* __restrict__ lens,
    unsigned short* __restrict__ outc) {
  __shared__ __align__(16) unsigned short Kt[64 * 64];   // [c][dk], swizzled
  __shared__ __align__(16) unsigned short Vt[64 * 64];   // [dk][c], swizzled
  __shared__ __align__(16) unsigned short Pl[4 * 16 * 64];  // per-wave P, swizzled
  const int tid = threadIdx.x;
  const int w = tid >> 6, lane = tid & 63;
  const int r = lane & 15, g = lane >> 4;
  const int bh = blockIdx.y;
  const int b = bh >> 4, h = bh & 15;
  const int q0 = blockIdx.x * 64;

  const unsigned short* Qp = qkv;
  const unsigned short* Kp = qkv + HSZ;
  const unsigned short* Vp = qkv + 2 * (size_t)HSZ;

  // Q B-fragments for this wave's 16 rows (row = r, k-chunks via g)
  const size_t qbase = (size_t)(bh * S_LEN + q0 + w * 16 + r) * DKH;
  const bf16x8 qf0 = *(const bf16x8*)(Qp + qbase + g * 8);
  const bf16x8 qf1 = *(const bf16x8*)(Qp + qbase + 32 + g * 8);

  const int L = lens[b];
  const int nt = (L + 63) >> 6;
  float mrun = -__builtin_inff(), lrun = 0.f;
  f32x4 oacc[4] = {};

  char* KtB = (char*)Kt;
  char* VtB = (char*)Vt;
  char* PlB = (char*)Pl + w * 2048;
  const int swp = (r & 7) << 4;

  for (int t = 0; t < nt; ++t) {
    const int kv0 = t * 64;
    // ---- stage K (global_load_lds, pre-swizzled source) ----
    const char* kgb = (const char*)(Kp + (size_t)(bh * S_LEN + kv0) * DKH);
#pragma unroll
    for (int i = 0; i < 2; ++i) {
      const int o = i * 4096 + w * 1024 + lane * 16;
      const int row = o >> 7, colb = o & 127;
      gload_lds16(kgb + row * 128 + (colb ^ ((row & 7) << 4)), KtB + i * 4096 + w * 1024);
    }
    // ---- stage V transposed (reg -> swizzled b16 writes) ----
    const unsigned short* vgb = Vp + (size_t)(bh * S_LEN + kv0) * DKH;
#pragma unroll
    for (int i = 0; i < 2; ++i) {
      const int u = i * 256 + tid;
      const int c = u & 63, g8 = u >> 6;
      const bf16x8 vv = *(const bf16x8*)(vgb + c * DKH + g8 * 8);
#pragma unroll
      for (int j = 0; j < 8; ++j) {
        const int dk = g8 * 8 + j;
        *(short*)(VtB + dk * 128 + ((2 * c) ^ ((dk & 7) << 4))) = vv[j];
      }
    }
    __syncthreads();

    // ---- scores: S^T = mfma(K, Q) -> lane owns q-row r, c = 16f+4g+reg ----
    f32x4 st[4];
#pragma unroll
    for (int f = 0; f < 4; ++f) {
      const int c = f * 16 + r;
      const int sw = (c & 7) << 4;
      const bf16x8 k0 = *(const bf16x8*)(KtB + c * 128 + ((g * 16) ^ sw));
      const bf16x8 k1 = *(const bf16x8*)(KtB + c * 128 + ((64 + g * 16) ^ sw));
      f32x4 a = {};
      a = __builtin_amdgcn_mfma_f32_16x16x32_bf16(k0, qf0, a, 0, 0, 0);
      a = __builtin_amdgcn_mfma_f32_16x16x32_bf16(k1, qf1, a, 0, 0, 0);
      st[f] = a;
    }
    if (t == nt - 1) {
#pragma unroll
      for (int f = 0; f < 4; ++f)
#pragma unroll
        for (int reg = 0; reg < 4; ++reg)
          if (kv0 + f * 16 + 4 * g + reg >= L) st[f][reg] = -__builtin_inff();
    }

    // ---- online softmax (in-lane over 16, shfl over g-groups) ----
    float mloc = st[0][0];
#pragma unroll
    for (int f = 0; f < 4; ++f)
#pragma unroll
      for (int reg = 0; reg < 4; ++reg) mloc = fmaxf(mloc, st[f][reg]);
    mloc = fmaxf(mloc, __shfl_xor(mloc, 16));
    mloc = fmaxf(mloc, __shfl_xor(mloc, 32));
    const float mnew = fmaxf(mrun, mloc);
    const float alpha = __expf(mrun - mnew);
    float psum = 0.f;
#pragma unroll
    for (int f = 0; f < 4; ++f)
#pragma unroll
      for (int reg = 0; reg < 4; ++reg) {
        const float p = __expf(st[f][reg] - mnew);
        st[f][reg] = p;
        psum += p;
      }
    psum += __shfl_xor(psum, 16);
    psum += __shfl_xor(psum, 32);
    lrun = lrun * alpha + psum;
    mrun = mnew;

    float areg[4];
#pragma unroll
    for (int reg = 0; reg < 4; ++reg) areg[reg] = __shfl(alpha, 4 * g + reg);
#pragma unroll
    for (int f = 0; f < 4; ++f)
#pragma unroll
      for (int reg = 0; reg < 4; ++reg) oacc[f][reg] *= areg[reg];

    // ---- P -> LDS (bf16, packed 4 = ds_write_b64, swizzled) ----
#pragma unroll
    for (int f = 0; f < 4; ++f) {
      ushort4 pw;
      pw.x = f2bf(st[f][0]); pw.y = f2bf(st[f][1]);
      pw.z = f2bf(st[f][2]); pw.w = f2bf(st[f][3]);
      *(ushort4*)(PlB + r * 128 + ((f * 32 + g * 8) ^ swp)) = pw;
    }

    // ---- PV: O += P @ V ----
#pragma unroll
    for (int c2 = 0; c2 < 2; ++c2) {
      const bf16x8 pa = *(const bf16x8*)(PlB + r * 128 + ((c2 * 64 + g * 16) ^ swp));
#pragma unroll
      for (int f = 0; f < 4; ++f) {
        const int dk = f * 16 + r;
        const bf16x8 vf =
            *(const bf16x8*)(VtB + dk * 128 + ((c2 * 64 + g * 16) ^ ((dk & 7) << 4)));
        oacc[f] = __builtin_amdgcn_mfma_f32_16x16x32_bf16(pa, vf, oacc[f], 0, 0, 0);
      }
    }
    __syncthreads();
  }

  // ---- normalize + write concat [B,S,D] bf16 ----
  float lreg[4];
#pragma unroll
  for (int reg = 0; reg < 4; ++reg) lreg[reg] = __shfl(lrun, 4 * g + reg);
#pragma unroll
  for (int f = 0; f < 4; ++f) {
    const int dk = f * 16 + r;
#pragma unroll
    for (int reg = 0; reg < 4; ++reg) {
      const int row = 4 * g + reg;
      const float v = oacc[f][reg] / lreg[reg];
      outc[(size_t)(b * S_LEN + q0 + w * 16 + row) * 1024 + h * DKH + dk] = f2bf(v);
    }
  }
}

// ---------------- launch ----------------
extern "C" void kernel_launch(void* const* d_in, const int* in_sizes, int n_in,
                              void* d_out, int out_size, void* d_ws, size_t ws_size,
                              hipStream_t stream) {
  const float* x  = (const float*)d_in[0];
  const int* mask = (const int*)d_in[1];
  const float* wq = (const float*)d_in[2];
  const float* bq = (const float*)d_in[3];
  const float* wk = (const float*)d_in[4];
  const float* bk = (const float*)d_in[5];
  const float* wv = (const float*)d_in[6];
  const float* bv = (const float*)d_in[7];
  const float* wo = (const float*)d_in[8];
  const float* bo = (const float*)d_in[9];
  (void)in_sizes; (void)n_in; (void)out_size; (void)ws_size;

  char* ws = (char*)d_ws;
  unsigned short* xb  = (unsigned short*)ws;                  // 4M elems (8 MB)
  unsigned short* wb  = (unsigned short*)(ws + 8388608);      // 3M elems (Wq|Wk|Wv)
  unsigned short* wob = (unsigned short*)(ws + 14680064);     // 1M elems
  unsigned short* qkv = (unsigned short*)(ws + 16777216);     // 3 x 4M elems
  unsigned short* ao  = (unsigned short*)(ws + 41943040);     // 4M elems
  int* lens           = (int*)(ws + 50331648);
  float* out          = (float*)d_out;

  cvt_kernel<<<4096, 256, 0, stream>>>(x, xb, 1048576);
  cvt_kernel<<<1024, 256, 0, stream>>>(wq, wb, 262144);
  cvt_kernel<<<1024, 256, 0, stream>>>(wk, wb + 1048576, 262144);
  cvt_kernel<<<1024, 256, 0, stream>>>(wv, wb + 2097152, 262144);
  cvt_kernel<<<1024, 256, 0, stream>>>(wo, wob, 262144);
  lens_kernel<<<2, 256, 0, stream>>>(mask, lens);

  gemm_kernel<0><<<dim3(24, 32), 256, 0, stream>>>(xb, wb, bq, bk, bv, qkv, nullptr, 1024);
  attn_kernel<<<dim3(32, 32), 256, 0, stream>>>(qkv, lens, ao);
  gemm_kernel<1><<<dim3(8, 32), 256, 0, stream>>>(ao, wob, bo, nullptr, nullptr, nullptr, out, 1024);
}

// Round 4
// 216.603 us; speedup vs baseline: 1.0523x; 1.0523x over previous
//
#include <hip/hip_runtime.h>

// ---------------- common types / helpers ----------------
using bf16x8 = __attribute__((ext_vector_type(8))) short;
using f32x4  = __attribute__((ext_vector_type(4))) float;

#define S_LEN 2048
#define NHEAD 16
#define DKH   64
#define HSZ   (S_LEN * DKH * 32)  // B*H*S*DK = 4194304 elems per matrix
// 1/sqrt(64) * log2(e): softmax done in exp2 domain
#define QSCALE 0.18033688011112042f

#if __has_builtin(__builtin_amdgcn_exp2f)
#define EXP2(x) __builtin_amdgcn_exp2f(x)
#else
#define EXP2(x) exp2f(x)
#endif

__device__ __forceinline__ unsigned short f2bf(float x) {
  unsigned u = __builtin_bit_cast(unsigned, x);
  u += 0x7FFFu + ((u >> 16) & 1u);  // RNE
  return (unsigned short)(u >> 16);
}

__device__ __forceinline__ void gload_lds16(const void* g, void* l) {
  __builtin_amdgcn_global_load_lds(
      (const __attribute__((address_space(1))) unsigned int*)g,
      (__attribute__((address_space(3))) unsigned int*)l, 16, 0, 0);
}

// ---------------- fp32 -> bf16 conversion ----------------
__global__ void cvt_kernel(const float* __restrict__ src,
                           unsigned short* __restrict__ dst, int n4) {
  int i = blockIdx.x * blockDim.x + threadIdx.x;
  if (i < n4) {
    float4 v = ((const float4*)src)[i];
    ushort4 o;
    o.x = f2bf(v.x); o.y = f2bf(v.y); o.z = f2bf(v.z); o.w = f2bf(v.w);
    ((ushort4*)dst)[i] = o;
  }
}

// ---------------- prefix lengths ----------------
__global__ void lens_kernel(const int* __restrict__ mask, int* __restrict__ lens) {
  __shared__ int sred[256];
  const int b = blockIdx.x;
  int c = 0;
  for (int s = threadIdx.x; s < S_LEN; s += 256) c += (mask[b * S_LEN + s] != 0) ? 1 : 0;
  sred[threadIdx.x] = c;
  __syncthreads();
  for (int st = 128; st > 0; st >>= 1) {
    if (threadIdx.x < st) sred[threadIdx.x] += sred[threadIdx.x + st];
    __syncthreads();
  }
  if (threadIdx.x == 0) lens[b] = sred[0];
}

// ---------------- m97-style 128x128x32 bf16 GEMM ----------------
// C[m,n] = sum_k A[m,k]*B[n,k]  (A: MxK row-major, B: NxK row-major)
// MODE 0: QKV epilogue -> bf16; Q,K as [B,H,S,DK] (Q scaled by QSCALE),
//         V TRANSPOSED as [B,H,DK,S] so attention stages it like K.
// MODE 1: fp32 out[m*1024+n] + bias
template <int MODE>
__global__ __launch_bounds__(256) void gemm_kernel(
    const unsigned short* __restrict__ A, const unsigned short* __restrict__ B,
    const float* __restrict__ b0, const float* __restrict__ b1,
    const float* __restrict__ b2, unsigned short* __restrict__ outQKV,
    float* __restrict__ outF, const int K) {
  __shared__ __align__(16) unsigned short As[128 * 32];
  __shared__ __align__(16) unsigned short Bs[128 * 32];
  const int tid = threadIdx.x;
  const int w = tid >> 6, lane = tid & 63;
  const int wm = w >> 1, wn = w & 1;
  const int r = lane & 15, g = lane >> 4;
  const int tm = blockIdx.y * 128, tn = blockIdx.x * 128;

  f32x4 acc[4][4] = {};
  const char* Ab = (const char*)A;
  const char* Bb = (const char*)B;
  char* AsB = (char*)As;
  char* BsB = (char*)Bs;

  for (int k0 = 0; k0 < K; k0 += 32) {
#pragma unroll
    for (int i = 0; i < 2; ++i) {
      const int o = (w * 2 + i) * 1024 + lane * 16;  // byte offset in 8KB tile
      const int row = o >> 6, colb = o & 63;
      gload_lds16(Ab + ((size_t)(tm + row) * K + k0) * 2 + colb, AsB + (w * 2 + i) * 1024);
      gload_lds16(Bb + ((size_t)(tn + row) * K + k0) * 2 + colb, BsB + (w * 2 + i) * 1024);
    }
    __syncthreads();
    bf16x8 af[4], bfr[4];
#pragma unroll
    for (int mi = 0; mi < 4; ++mi)
      af[mi] = *(const bf16x8*)(AsB + (wm * 64 + mi * 16 + r) * 64 + g * 16);
#pragma unroll
    for (int ni = 0; ni < 4; ++ni)
      bfr[ni] = *(const bf16x8*)(BsB + (wn * 64 + ni * 16 + r) * 64 + g * 16);
#pragma unroll
    for (int mi = 0; mi < 4; ++mi)
#pragma unroll
      for (int ni = 0; ni < 4; ++ni)
        acc[mi][ni] = __builtin_amdgcn_mfma_f32_16x16x32_bf16(af[mi], bfr[ni], acc[mi][ni], 0, 0, 0);
    __syncthreads();
  }

  if (MODE == 0) {
    const int mat = tn >> 10;  // tile never straddles a 1024 boundary
    const float* bp = (mat == 0) ? b0 : (mat == 1) ? b1 : b2;
    const float scale = (mat == 0) ? QSCALE : 1.0f;
    unsigned short* dst = outQKV + (size_t)mat * HSZ;
#pragma unroll
    for (int mi = 0; mi < 4; ++mi)
#pragma unroll
      for (int ni = 0; ni < 4; ++ni)
#pragma unroll
        for (int reg = 0; reg < 4; ++reg) {
          const int m = tm + wm * 64 + mi * 16 + 4 * g + reg;
          const int n = tn + wn * 64 + ni * 16 + r;
          const int nn = n & 1023;
          const float v = (acc[mi][ni][reg] + bp[nn]) * scale;
          const int bI = m >> 11, s = m & 2047, hh = nn >> 6, dk = nn & 63;
          if (mat == 2) {
            // V^T: [B,H,DK,S]
            dst[(size_t)((bI * NHEAD + hh) * DKH + dk) * S_LEN + s] = f2bf(v);
          } else {
            dst[(size_t)((bI * NHEAD + hh) * S_LEN + s) * DKH + dk] = f2bf(v);
          }
        }
  } else {
#pragma unroll
    for (int mi = 0; mi < 4; ++mi)
#pragma unroll
      for (int ni = 0; ni < 4; ++ni)
#pragma unroll
        for (int reg = 0; reg < 4; ++reg) {
          const int m = tm + wm * 64 + mi * 16 + 4 * g + reg;
          const int n = tn + wn * 64 + ni * 16 + r;
          outF[(size_t)m * 1024 + n] = acc[mi][ni][reg] + b0[n];
        }
  }
}

// ---------------- online-softmax helper (exp2 domain, exact rescale) -----
__device__ __forceinline__ void online_sm(f32x4* st, float& mrun, float& lrun,
                                          f32x4* oacc, int g) {
  float mloc = st[0][0];
#pragma unroll
  for (int f = 0; f < 4; ++f)
#pragma unroll
    for (int q = 0; q < 4; ++q) mloc = fmaxf(mloc, st[f][q]);
  mloc = fmaxf(mloc, __shfl_xor(mloc, 16));
  mloc = fmaxf(mloc, __shfl_xor(mloc, 32));
  const float mnew = fmaxf(mrun, mloc);
  const float alpha = EXP2(mrun - mnew);  // first tile: exp2(-inf) = 0
  mrun = mnew;
  float psum = 0.f;
#pragma unroll
  for (int f = 0; f < 4; ++f)
#pragma unroll
    for (int q = 0; q < 4; ++q) {
      const float p = EXP2(st[f][q] - mnew);
      st[f][q] = p;
      psum += p;
    }
  psum += __shfl_xor(psum, 16);
  psum += __shfl_xor(psum, 32);
  lrun = lrun * alpha + psum;
  float areg[4];
#pragma unroll
  for (int q = 0; q < 4; ++q) areg[q] = __shfl(alpha, 4 * g + q);
#pragma unroll
  for (int f = 0; f < 4; ++f)
#pragma unroll
    for (int q = 0; q < 4; ++q) oacc[f][q] *= areg[q];
}

// ---------------- flash attention ----------------
// grid (S/128, B*H); 4 waves x 32 q-rows (2 groups of 16). Swapped QK^T.
// K and V^T double-buffered in LDS, both staged via global_load_lds with
// pre-swizzled global source (XOR (row&7)<<4). PV reads V^T rows directly.
__global__ __launch_bounds__(256) void attn_kernel(
    const unsigned short* __restrict__ qkv, const int* __restrict__ lens,
    unsigned short* __restrict__ outc) {
  __shared__ __align__(16) unsigned short Kt[2][4096];  // [buf][c][dk] swz
  __shared__ __align__(16) unsigned short Vt[2][4096];  // [buf][dk][c] swz (V^T)
  __shared__ __align__(16) unsigned short Pl[4][2][1024];  // [wave][grp][q][c] swz
  const int tid = threadIdx.x;
  const int w = tid >> 6, lane = tid & 63;
  const int r = lane & 15, g = lane >> 4;
  const int bh = blockIdx.y;
  const int b = bh >> 4, h = bh & 15;
  const int q0 = blockIdx.x * 128;

  const unsigned short* Qp = qkv;
  const unsigned short* Kp = qkv + HSZ;
  const unsigned short* VTp = qkv + 2 * (size_t)HSZ;  // [B,H,DK,S]

  // Q B-fragments: group A rows [w*32, +16), group B rows [w*32+16, +16)
  const size_t qbase = (size_t)(bh * S_LEN + q0 + w * 32 + r) * DKH;
  const bf16x8 qa0 = *(const bf16x8*)(Qp + qbase + g * 8);
  const bf16x8 qa1 = *(const bf16x8*)(Qp + qbase + 32 + g * 8);
  const bf16x8 qb0 = *(const bf16x8*)(Qp + qbase + 16 * DKH + g * 8);
  const bf16x8 qb1 = *(const bf16x8*)(Qp + qbase + 16 * DKH + 32 + g * 8);

  const int L = lens[b];
  const int nt = (L + 63) >> 6;
  float mA = -__builtin_inff(), lA = 0.f;
  float mB = -__builtin_inff(), lB = 0.f;
  f32x4 oA[4] = {}, oB[4] = {};

  char* PA = (char*)Pl[w][0];
  char* PB = (char*)Pl[w][1];
  const int swp = (r & 7) << 4;

  const char* kgb0 = (const char*)(Kp + (size_t)bh * S_LEN * DKH);
  const char* vgb0 = (const char*)(VTp + (size_t)bh * DKH * S_LEN);

  // stage tile tt into buffer bb: K rows [c][dk], V^T rows [dk][c]; both
  // linear LDS dest + inverse-swizzled global source.
  auto stage = [&](int tt, int bb) {
    const char* kgb = kgb0 + (size_t)tt * 64 * DKH * 2;  // K tile base
    const char* vgb = vgb0 + (size_t)tt * 64 * 2;        // V^T col offset
    char* kd = (char*)Kt[bb];
    char* vd = (char*)Vt[bb];
#pragma unroll
    for (int i = 0; i < 2; ++i) {
      const int o = i * 4096 + w * 1024 + lane * 16;
      const int row = o >> 7, colb = o & 127;
      const int cs = colb ^ ((row & 7) << 4);
      gload_lds16(kgb + row * 128 + cs, kd + i * 4096 + w * 1024);
      gload_lds16(vgb + (size_t)row * (S_LEN * 2) + cs, vd + i * 4096 + w * 1024);
    }
  };

  if (nt > 0) stage(0, 0);
  __syncthreads();

  int buf = 0;
  for (int t = 0; t < nt; ++t) {
    if (t + 1 < nt) stage(t + 1, buf ^ 1);  // issue early, drains at end barrier

    const char* KtB = (const char*)Kt[buf];
    // ---- QK^T (swapped): lane owns q-row r; c = 16f + 4g + reg ----
    f32x4 sa[4], sb[4];
    __builtin_amdgcn_s_setprio(1);
#pragma unroll
    for (int f = 0; f < 4; ++f) {
      const int c = f * 16 + r;
      const int sw = (c & 7) << 4;
      const bf16x8 k0 = *(const bf16x8*)(KtB + c * 128 + ((g * 16) ^ sw));
      const bf16x8 k1 = *(const bf16x8*)(KtB + c * 128 + ((64 + g * 16) ^ sw));
      f32x4 x = {};
      x = __builtin_amdgcn_mfma_f32_16x16x32_bf16(k0, qa0, x, 0, 0, 0);
      x = __builtin_amdgcn_mfma_f32_16x16x32_bf16(k1, qa1, x, 0, 0, 0);
      sa[f] = x;
      f32x4 y = {};
      y = __builtin_amdgcn_mfma_f32_16x16x32_bf16(k0, qb0, y, 0, 0, 0);
      y = __builtin_amdgcn_mfma_f32_16x16x32_bf16(k1, qb1, y, 0, 0, 0);
      sb[f] = y;
    }
    __builtin_amdgcn_s_setprio(0);

    const int kv0 = t * 64;
    if (t == nt - 1) {
#pragma unroll
      for (int f = 0; f < 4; ++f)
#pragma unroll
        for (int q = 0; q < 4; ++q)
          if (kv0 + f * 16 + 4 * g + q >= L) {
            sa[f][q] = -__builtin_inff();
            sb[f][q] = -__builtin_inff();
          }
    }

    online_sm(sa, mA, lA, oA, g);
    online_sm(sb, mB, lB, oB, g);

    // ---- P -> LDS (bf16, swizzled, per-wave private) ----
#pragma unroll
    for (int f = 0; f < 4; ++f) {
      ushort4 pw;
      pw.x = f2bf(sa[f][0]); pw.y = f2bf(sa[f][1]);
      pw.z = f2bf(sa[f][2]); pw.w = f2bf(sa[f][3]);
      *(ushort4*)(PA + r * 128 + ((f * 32 + g * 8) ^ swp)) = pw;
      ushort4 qw;
      qw.x = f2bf(sb[f][0]); qw.y = f2bf(sb[f][1]);
      qw.z = f2bf(sb[f][2]); qw.w = f2bf(sb[f][3]);
      *(ushort4*)(PB + r * 128 + ((f * 32 + g * 8) ^ swp)) = qw;
    }

    // ---- PV: O += P @ V (V^T rows read directly, R1-verified pattern) ----
    const char* VtB = (const char*)Vt[buf];
#pragma unroll
    for (int c2 = 0; c2 < 2; ++c2) {
      const bf16x8 pa = *(const bf16x8*)(PA + r * 128 + ((c2 * 64 + g * 16) ^ swp));
      const bf16x8 pb = *(const bf16x8*)(PB + r * 128 + ((c2 * 64 + g * 16) ^ swp));
      __builtin_amdgcn_s_setprio(1);
#pragma unroll
      for (int f = 0; f < 4; ++f) {
        const int dk = f * 16 + r;
        const bf16x8 vf =
            *(const bf16x8*)(VtB + dk * 128 + ((c2 * 64 + g * 16) ^ ((dk & 7) << 4)));
        oA[f] = __builtin_amdgcn_mfma_f32_16x16x32_bf16(pa, vf, oA[f], 0, 0, 0);
        oB[f] = __builtin_amdgcn_mfma_f32_16x16x32_bf16(pb, vf, oB[f], 0, 0, 0);
      }
      __builtin_amdgcn_s_setprio(0);
    }

    __syncthreads();  // drains t+1 staging (vmcnt) + protects buf reuse
    buf ^= 1;
  }

  // ---- normalize + write concat [B,S,D] bf16 ----
  const float iA = 1.0f / lA;
  const float iB = 1.0f / lB;
  float rA[4], rB[4];
#pragma unroll
  for (int q = 0; q < 4; ++q) {
    rA[q] = __shfl(iA, 4 * g + q);
    rB[q] = __shfl(iB, 4 * g + q);
  }
#pragma unroll
  for (int f = 0; f < 4; ++f) {
    const int dk = f * 16 + r;
#pragma unroll
    for (int q = 0; q < 4; ++q) {
      const int rowA = q0 + w * 32 + 4 * g + q;
      outc[(size_t)(b * S_LEN + rowA) * 1024 + h * DKH + dk] = f2bf(oA[f][q] * rA[q]);
      const int rowB = rowA + 16;
      outc[(size_t)(b * S_LEN + rowB) * 1024 + h * DKH + dk] = f2bf(oB[f][q] * rB[q]);
    }
  }
}

// ---------------- launch ----------------
extern "C" void kernel_launch(void* const* d_in, const int* in_sizes, int n_in,
                              void* d_out, int out_size, void* d_ws, size_t ws_size,
                              hipStream_t stream) {
  const float* x  = (const float*)d_in[0];
  const int* mask = (const int*)d_in[1];
  const float* wq = (const float*)d_in[2];
  const float* bq = (const float*)d_in[3];
  const float* wk = (const float*)d_in[4];
  const float* bk = (const float*)d_in[5];
  const float* wv = (const float*)d_in[6];
  const float* bv = (const float*)d_in[7];
  const float* wo = (const float*)d_in[8];
  const float* bo = (const float*)d_in[9];
  (void)in_sizes; (void)n_in; (void)out_size; (void)ws_size;

  char* ws = (char*)d_ws;
  unsigned short* xb  = (unsigned short*)ws;                  // 4M elems (8 MB)
  unsigned short* wb  = (unsigned short*)(ws + 8388608);      // 3M elems (Wq|Wk|Wv)
  unsigned short* wob = (unsigned short*)(ws + 14680064);     // 1M elems
  unsigned short* qkv = (unsigned short*)(ws + 16777216);     // Q|K|V^T, 3 x 4M elems
  unsigned short* ao  = (unsigned short*)(ws + 41943040);     // 4M elems
  int* lens           = (int*)(ws + 50331648);
  float* out          = (float*)d_out;

  cvt_kernel<<<4096, 256, 0, stream>>>(x, xb, 1048576);
  cvt_kernel<<<1024, 256, 0, stream>>>(wq, wb, 262144);
  cvt_kernel<<<1024, 256, 0, stream>>>(wk, wb + 1048576, 262144);
  cvt_kernel<<<1024, 256, 0, stream>>>(wv, wb + 2097152, 262144);
  cvt_kernel<<<1024, 256, 0, stream>>>(wo, wob, 262144);
  lens_kernel<<<2, 256, 0, stream>>>(mask, lens);

  gemm_kernel<0><<<dim3(24, 32), 256, 0, stream>>>(xb, wb, bq, bk, bv, qkv, nullptr, 1024);
  attn_kernel<<<dim3(16, 32), 256, 0, stream>>>(qkv, lens, ao);
  gemm_kernel<1><<<dim3(8, 32), 256, 0, stream>>>(ao, wob, bo, nullptr, nullptr, nullptr, out, 1024);
}

// Round 5
// 211.704 us; speedup vs baseline: 1.0767x; 1.0231x over previous
//
#include <hip/hip_runtime.h>

// ---------------- common types / helpers ----------------
using bf16x8 = __attribute__((ext_vector_type(8))) short;
using f32x4  = __attribute__((ext_vector_type(4))) float;

#define S_LEN 2048
#define NHEAD 16
#define DKH   64
#define HSZ   (S_LEN * DKH * 32)  // B*H*S*DK = 4194304 elems per matrix
// 1/sqrt(64) * log2(e): softmax done in exp2 domain
#define QSCALE 0.18033688011112042f

#if __has_builtin(__builtin_amdgcn_exp2f)
#define EXP2(x) __builtin_amdgcn_exp2f(x)
#else
#define EXP2(x) exp2f(x)
#endif

template <bool B> struct BoolC { static constexpr bool value = B; };

__device__ __forceinline__ unsigned short f2bf(float x) {
  unsigned u = __builtin_bit_cast(unsigned, x);
  u += 0x7FFFu + ((u >> 16) & 1u);  // RNE
  return (unsigned short)(u >> 16);
}

__device__ __forceinline__ void gload_lds16(const void* g, void* l) {
  __builtin_amdgcn_global_load_lds(
      (const __attribute__((address_space(1))) unsigned int*)g,
      (__attribute__((address_space(3))) unsigned int*)l, 16, 0, 0);
}

// ---------------- fused fp32 -> bf16 conversion (x, Wq, Wk, Wv, Wo) -----
__global__ void cvt_all_kernel(const float* __restrict__ x,
                               const float* __restrict__ wq,
                               const float* __restrict__ wk,
                               const float* __restrict__ wv,
                               const float* __restrict__ wo,
                               unsigned short* __restrict__ xb,
                               unsigned short* __restrict__ wb,
                               unsigned short* __restrict__ wob) {
  const int i = blockIdx.x * 256 + threadIdx.x;  // float4-group index
  const float* s;
  unsigned short* d;
  if (i < 1048576) {
    s = x + (size_t)i * 4;            d = xb + (size_t)i * 4;
  } else if (i < 1310720) {
    const int j = i - 1048576;
    s = wq + (size_t)j * 4;           d = wb + (size_t)j * 4;
  } else if (i < 1572864) {
    const int j = i - 1310720;
    s = wk + (size_t)j * 4;           d = wb + 1048576 + (size_t)j * 4;
  } else if (i < 1835008) {
    const int j = i - 1572864;
    s = wv + (size_t)j * 4;           d = wb + 2097152 + (size_t)j * 4;
  } else {
    const int j = i - 1835008;
    s = wo + (size_t)j * 4;           d = wob + (size_t)j * 4;
  }
  float4 v = *(const float4*)s;
  ushort4 o;
  o.x = f2bf(v.x); o.y = f2bf(v.y); o.z = f2bf(v.z); o.w = f2bf(v.w);
  *(ushort4*)d = o;
}

// ---------------- prefix lengths ----------------
__global__ void lens_kernel(const int* __restrict__ mask, int* __restrict__ lens) {
  __shared__ int sred[256];
  const int b = blockIdx.x;
  int c = 0;
  for (int s = threadIdx.x; s < S_LEN; s += 256) c += (mask[b * S_LEN + s] != 0) ? 1 : 0;
  sred[threadIdx.x] = c;
  __syncthreads();
  for (int st = 128; st > 0; st >>= 1) {
    if (threadIdx.x < st) sred[threadIdx.x] += sred[threadIdx.x + st];
    __syncthreads();
  }
  if (threadIdx.x == 0) lens[b] = sred[0];
}

// ---------------- 128x128x32 bf16 GEMM, double-buffered (2-phase) -------
// C[m,n] = sum_k A[m,k]*B[n,k]  (A: MxK row-major, B: NxK row-major)
// MODE 0: QKV. Q,K (swapped orient -> pack dk) as [B,H,S,DK], Q*QSCALE;
//         V (normal orient -> pack s) TRANSPOSED as [B,H,DK,S].
// MODE 1: O-proj fp32 out[m*1024+n] + bias, swapped orient -> float4 stores.
//
// Orientation note: mfma(X, Y) yields D[row][col] with row=4g+reg walking
// X's index and col=r walking Y's index (session-verified mapping). Both
// fragment layouts are identical, so swapping args just relabels row/col.
template <int MODE>
__global__ __launch_bounds__(256) void gemm_kernel(
    const unsigned short* __restrict__ A, const unsigned short* __restrict__ B,
    const float* __restrict__ b0, const float* __restrict__ b1,
    const float* __restrict__ b2, unsigned short* __restrict__ outQKV,
    float* __restrict__ outF, const int K) {
  __shared__ __align__(16) unsigned short As[2][128 * 32];
  __shared__ __align__(16) unsigned short Bs[2][128 * 32];
  const int tid = threadIdx.x;
  const int w = tid >> 6, lane = tid & 63;
  const int wm = w >> 1, wn = w & 1;
  const int r = lane & 15, g = lane >> 4;
  const int tm = blockIdx.y * 128, tn = blockIdx.x * 128;
  const int mat = (MODE == 0) ? (tn >> 10) : 0;

  f32x4 acc[4][4] = {};
  const char* Ab = (const char*)A;
  const char* Bb = (const char*)B;
  const int nk = K >> 5;

  auto stage = [&](int kt, int bb) {
    char* ad = (char*)As[bb];
    char* bd = (char*)Bs[bb];
    const int k0 = kt * 32;
#pragma unroll
    for (int i = 0; i < 2; ++i) {
      const int o = (w * 2 + i) * 1024 + lane * 16;  // byte offset in 8KB tile
      const int row = o >> 6, colb = o & 63;
      gload_lds16(Ab + ((size_t)(tm + row) * K + k0) * 2 + colb, ad + (w * 2 + i) * 1024);
      gload_lds16(Bb + ((size_t)(tn + row) * K + k0) * 2 + colb, bd + (w * 2 + i) * 1024);
    }
  };

  auto kloop = [&](auto swap_c) {
    constexpr bool SW = decltype(swap_c)::value;
    stage(0, 0);
    __syncthreads();
    int buf = 0;
    for (int kt = 0; kt < nk; ++kt) {
      if (kt + 1 < nk) stage(kt + 1, buf ^ 1);  // issue early; drains at barrier
      const char* AsB = (const char*)As[buf];
      const char* BsB = (const char*)Bs[buf];
      bf16x8 af[4], bfr[4];
#pragma unroll
      for (int mi = 0; mi < 4; ++mi)
        af[mi] = *(const bf16x8*)(AsB + (wm * 64 + mi * 16 + r) * 64 + g * 16);
#pragma unroll
      for (int ni = 0; ni < 4; ++ni)
        bfr[ni] = *(const bf16x8*)(BsB + (wn * 64 + ni * 16 + r) * 64 + g * 16);
      __builtin_amdgcn_s_setprio(1);
#pragma unroll
      for (int mi = 0; mi < 4; ++mi)
#pragma unroll
        for (int ni = 0; ni < 4; ++ni) {
          if constexpr (SW)
            acc[mi][ni] = __builtin_amdgcn_mfma_f32_16x16x32_bf16(bfr[ni], af[mi], acc[mi][ni], 0, 0, 0);
          else
            acc[mi][ni] = __builtin_amdgcn_mfma_f32_16x16x32_bf16(af[mi], bfr[ni], acc[mi][ni], 0, 0, 0);
        }
      __builtin_amdgcn_s_setprio(0);
      __syncthreads();
      buf ^= 1;
    }
  };

  if (MODE == 1 || mat != 2) kloop(BoolC<true>{});
  else                        kloop(BoolC<false>{});

  if (MODE == 0) {
    if (mat != 2) {
      // ---- Q/K epilogue (swapped): row=4g+reg -> n (pack 4 dk), col=r -> m
      const float* bp = mat ? b1 : b0;
      const float scale = mat ? 1.0f : QSCALE;
      unsigned short* dst = outQKV + (size_t)mat * HSZ;
      const int tnl = tn & 1023;
#pragma unroll
      for (int ni = 0; ni < 4; ++ni) {
        const int nb = tnl + wn * 64 + ni * 16 + 4 * g;  // n&1023, reg base
        const float4 b4 = *(const float4*)(bp + nb);
        const int hh = nb >> 6, dkb = nb & 63;
#pragma unroll
        for (int mi = 0; mi < 4; ++mi) {
          const int m = tm + wm * 64 + mi * 16 + r;
          const int bI = m >> 11, s = m & 2047;
          ushort4 pw;
          pw.x = f2bf((acc[mi][ni][0] + b4.x) * scale);
          pw.y = f2bf((acc[mi][ni][1] + b4.y) * scale);
          pw.z = f2bf((acc[mi][ni][2] + b4.z) * scale);
          pw.w = f2bf((acc[mi][ni][3] + b4.w) * scale);
          *(ushort4*)(dst + (size_t)((bI * NHEAD + hh) * S_LEN + s) * DKH + dkb) = pw;
        }
      }
    } else {
      // ---- V epilogue (normal): row=4g+reg -> m (pack 4 s), col=r -> n
      unsigned short* dst = outQKV + 2 * (size_t)HSZ;  // V^T [B,H,DK,S]
      const int tnl = tn & 1023;
#pragma unroll
      for (int ni = 0; ni < 4; ++ni) {
        const int n = tnl + wn * 64 + ni * 16 + r;  // n&1023
        const float bias = b2[n];
        const int hh = n >> 6, dk = n & 63;
#pragma unroll
        for (int mi = 0; mi < 4; ++mi) {
          const int m = tm + wm * 64 + mi * 16 + 4 * g;
          const int bI = m >> 11, s0 = m & 2047;
          ushort4 pw;
          pw.x = f2bf(acc[mi][ni][0] + bias);
          pw.y = f2bf(acc[mi][ni][1] + bias);
          pw.z = f2bf(acc[mi][ni][2] + bias);
          pw.w = f2bf(acc[mi][ni][3] + bias);
          *(ushort4*)(dst + (size_t)((bI * NHEAD + hh) * DKH + dk) * S_LEN + s0) = pw;
        }
      }
    }
  } else {
    // ---- O-proj epilogue (swapped): pack 4 consecutive n as float4
#pragma unroll
    for (int ni = 0; ni < 4; ++ni) {
      const int nb = tn + wn * 64 + ni * 16 + 4 * g;
      const float4 b4 = *(const float4*)(b0 + nb);
#pragma unroll
      for (int mi = 0; mi < 4; ++mi) {
        const int m = tm + wm * 64 + mi * 16 + r;
        float4 o4;
        o4.x = acc[mi][ni][0] + b4.x;
        o4.y = acc[mi][ni][1] + b4.y;
        o4.z = acc[mi][ni][2] + b4.z;
        o4.w = acc[mi][ni][3] + b4.w;
        *(float4*)(outF + (size_t)m * 1024 + nb) = o4;
      }
    }
  }
}

// ---------------- online-softmax helper (exp2 domain, exact rescale) -----
__device__ __forceinline__ void online_sm(f32x4* st, float& mrun, float& lrun,
                                          f32x4* oacc, int g) {
  float mloc = st[0][0];
#pragma unroll
  for (int f = 0; f < 4; ++f)
#pragma unroll
    for (int q = 0; q < 4; ++q) mloc = fmaxf(mloc, st[f][q]);
  mloc = fmaxf(mloc, __shfl_xor(mloc, 16));
  mloc = fmaxf(mloc, __shfl_xor(mloc, 32));
  const float mnew = fmaxf(mrun, mloc);
  const float alpha = EXP2(mrun - mnew);  // first tile: exp2(-inf) = 0
  mrun = mnew;
  float psum = 0.f;
#pragma unroll
  for (int f = 0; f < 4; ++f)
#pragma unroll
    for (int q = 0; q < 4; ++q) {
      const float p = EXP2(st[f][q] - mnew);
      st[f][q] = p;
      psum += p;
    }
  psum += __shfl_xor(psum, 16);
  psum += __shfl_xor(psum, 32);
  lrun = lrun * alpha + psum;
  float areg[4];
#pragma unroll
  for (int q = 0; q < 4; ++q) areg[q] = __shfl(alpha, 4 * g + q);
#pragma unroll
  for (int f = 0; f < 4; ++f)
#pragma unroll
    for (int q = 0; q < 4; ++q) oacc[f][q] *= areg[q];
}

// ---------------- flash attention (unchanged from verified R4) ----------
// grid (S/128, B*H); 4 waves x 32 q-rows (2 groups of 16). Swapped QK^T.
// K and V^T double-buffered in LDS, both staged via global_load_lds with
// pre-swizzled global source (XOR (row&7)<<4). PV reads V^T rows directly.
__global__ __launch_bounds__(256) void attn_kernel(
    const unsigned short* __restrict__ qkv, const int* __restrict__ lens,
    unsigned short* __restrict__ outc) {
  __shared__ __align__(16) unsigned short Kt[2][4096];  // [buf][c][dk] swz
  __shared__ __align__(16) unsigned short Vt[2][4096];  // [buf][dk][c] swz (V^T)
  __shared__ __align__(16) unsigned short Pl[4][2][1024];  // [wave][grp][q][c] swz
  const int tid = threadIdx.x;
  const int w = tid >> 6, lane = tid & 63;
  const int r = lane & 15, g = lane >> 4;
  const int bh = blockIdx.y;
  const int b = bh >> 4, h = bh & 15;
  const int q0 = blockIdx.x * 128;

  const unsigned short* Qp = qkv;
  const unsigned short* Kp = qkv + HSZ;
  const unsigned short* VTp = qkv + 2 * (size_t)HSZ;  // [B,H,DK,S]

  const size_t qbase = (size_t)(bh * S_LEN + q0 + w * 32 + r) * DKH;
  const bf16x8 qa0 = *(const bf16x8*)(Qp + qbase + g * 8);
  const bf16x8 qa1 = *(const bf16x8*)(Qp + qbase + 32 + g * 8);
  const bf16x8 qb0 = *(const bf16x8*)(Qp + qbase + 16 * DKH + g * 8);
  const bf16x8 qb1 = *(const bf16x8*)(Qp + qbase + 16 * DKH + 32 + g * 8);

  const int L = lens[b];
  const int nt = (L + 63) >> 6;
  float mA = -__builtin_inff(), lA = 0.f;
  float mB = -__builtin_inff(), lB = 0.f;
  f32x4 oA[4] = {}, oB[4] = {};

  char* PA = (char*)Pl[w][0];
  char* PB = (char*)Pl[w][1];
  const int swp = (r & 7) << 4;

  const char* kgb0 = (const char*)(Kp + (size_t)bh * S_LEN * DKH);
  const char* vgb0 = (const char*)(VTp + (size_t)bh * DKH * S_LEN);

  auto stage = [&](int tt, int bb) {
    const char* kgb = kgb0 + (size_t)tt * 64 * DKH * 2;  // K tile base
    const char* vgb = vgb0 + (size_t)tt * 64 * 2;        // V^T col offset
    char* kd = (char*)Kt[bb];
    char* vd = (char*)Vt[bb];
#pragma unroll
    for (int i = 0; i < 2; ++i) {
      const int o = i * 4096 + w * 1024 + lane * 16;
      const int row = o >> 7, colb = o & 127;
      const int cs = colb ^ ((row & 7) << 4);
      gload_lds16(kgb + row * 128 + cs, kd + i * 4096 + w * 1024);
      gload_lds16(vgb + (size_t)row * (S_LEN * 2) + cs, vd + i * 4096 + w * 1024);
    }
  };

  if (nt > 0) stage(0, 0);
  __syncthreads();

  int buf = 0;
  for (int t = 0; t < nt; ++t) {
    if (t + 1 < nt) stage(t + 1, buf ^ 1);  // issue early, drains at end barrier

    const char* KtB = (const char*)Kt[buf];
    f32x4 sa[4], sb[4];
    __builtin_amdgcn_s_setprio(1);
#pragma unroll
    for (int f = 0; f < 4; ++f) {
      const int c = f * 16 + r;
      const int sw = (c & 7) << 4;
      const bf16x8 k0 = *(const bf16x8*)(KtB + c * 128 + ((g * 16) ^ sw));
      const bf16x8 k1 = *(const bf16x8*)(KtB + c * 128 + ((64 + g * 16) ^ sw));
      f32x4 x = {};
      x = __builtin_amdgcn_mfma_f32_16x16x32_bf16(k0, qa0, x, 0, 0, 0);
      x = __builtin_amdgcn_mfma_f32_16x16x32_bf16(k1, qa1, x, 0, 0, 0);
      sa[f] = x;
      f32x4 y = {};
      y = __builtin_amdgcn_mfma_f32_16x16x32_bf16(k0, qb0, y, 0, 0, 0);
      y = __builtin_amdgcn_mfma_f32_16x16x32_bf16(k1, qb1, y, 0, 0, 0);
      sb[f] = y;
    }
    __builtin_amdgcn_s_setprio(0);

    const int kv0 = t * 64;
    if (t == nt - 1) {
#pragma unroll
      for (int f = 0; f < 4; ++f)
#pragma unroll
        for (int q = 0; q < 4; ++q)
          if (kv0 + f * 16 + 4 * g + q >= L) {
            sa[f][q] = -__builtin_inff();
            sb[f][q] = -__builtin_inff();
          }
    }

    online_sm(sa, mA, lA, oA, g);
    online_sm(sb, mB, lB, oB, g);

#pragma unroll
    for (int f = 0; f < 4; ++f) {
      ushort4 pw;
      pw.x = f2bf(sa[f][0]); pw.y = f2bf(sa[f][1]);
      pw.z = f2bf(sa[f][2]); pw.w = f2bf(sa[f][3]);
      *(ushort4*)(PA + r * 128 + ((f * 32 + g * 8) ^ swp)) = pw;
      ushort4 qw;
      qw.x = f2bf(sb[f][0]); qw.y = f2bf(sb[f][1]);
      qw.z = f2bf(sb[f][2]); qw.w = f2bf(sb[f][3]);
      *(ushort4*)(PB + r * 128 + ((f * 32 + g * 8) ^ swp)) = qw;
    }

    const char* VtB = (const char*)Vt[buf];
#pragma unroll
    for (int c2 = 0; c2 < 2; ++c2) {
      const bf16x8 pa = *(const bf16x8*)(PA + r * 128 + ((c2 * 64 + g * 16) ^ swp));
      const bf16x8 pb = *(const bf16x8*)(PB + r * 128 + ((c2 * 64 + g * 16) ^ swp));
      __builtin_amdgcn_s_setprio(1);
#pragma unroll
      for (int f = 0; f < 4; ++f) {
        const int dk = f * 16 + r;
        const bf16x8 vf =
            *(const bf16x8*)(VtB + dk * 128 + ((c2 * 64 + g * 16) ^ ((dk & 7) << 4)));
        oA[f] = __builtin_amdgcn_mfma_f32_16x16x32_bf16(pa, vf, oA[f], 0, 0, 0);
        oB[f] = __builtin_amdgcn_mfma_f32_16x16x32_bf16(pb, vf, oB[f], 0, 0, 0);
      }
      __builtin_amdgcn_s_setprio(0);
    }

    __syncthreads();  // drains t+1 staging (vmcnt) + protects buf reuse
    buf ^= 1;
  }

  const float iA = 1.0f / lA;
  const float iB = 1.0f / lB;
  float rA[4], rB[4];
#pragma unroll
  for (int q = 0; q < 4; ++q) {
    rA[q] = __shfl(iA, 4 * g + q);
    rB[q] = __shfl(iB, 4 * g + q);
  }
#pragma unroll
  for (int f = 0; f < 4; ++f) {
    const int dk = f * 16 + r;
#pragma unroll
    for (int q = 0; q < 4; ++q) {
      const int rowA = q0 + w * 32 + 4 * g + q;
      outc[(size_t)(b * S_LEN + rowA) * 1024 + h * DKH + dk] = f2bf(oA[f][q] * rA[q]);
      const int rowB = rowA + 16;
      outc[(size_t)(b * S_LEN + rowB) * 1024 + h * DKH + dk] = f2bf(oB[f][q] * rB[q]);
    }
  }
}

// ---------------- launch ----------------
extern "C" void kernel_launch(void* const* d_in, const int* in_sizes, int n_in,
                              void* d_out, int out_size, void* d_ws, size_t ws_size,
                              hipStream_t stream) {
  const float* x  = (const float*)d_in[0];
  const int* mask = (const int*)d_in[1];
  const float* wq = (const float*)d_in[2];
  const float* bq = (const float*)d_in[3];
  const float* wk = (const float*)d_in[4];
  const float* bk = (const float*)d_in[5];
  const float* wv = (const float*)d_in[6];
  const float* bv = (const float*)d_in[7];
  const float* wo = (const float*)d_in[8];
  const float* bo = (const float*)d_in[9];
  (void)in_sizes; (void)n_in; (void)out_size; (void)ws_size;

  char* ws = (char*)d_ws;
  unsigned short* xb  = (unsigned short*)ws;                  // 4M elems (8 MB)
  unsigned short* wb  = (unsigned short*)(ws + 8388608);      // 3M elems (Wq|Wk|Wv)
  unsigned short* wob = (unsigned short*)(ws + 14680064);     // 1M elems
  unsigned short* qkv = (unsigned short*)(ws + 16777216);     // Q|K|V^T, 3 x 4M elems
  unsigned short* ao  = (unsigned short*)(ws + 41943040);     // 4M elems
  int* lens           = (int*)(ws + 50331648);
  float* out          = (float*)d_out;

  cvt_all_kernel<<<8192, 256, 0, stream>>>(x, wq, wk, wv, wo, xb, wb, wob);
  lens_kernel<<<2, 256, 0, stream>>>(mask, lens);

  gemm_kernel<0><<<dim3(24, 32), 256, 0, stream>>>(xb, wb, bq, bk, bv, qkv, nullptr, 1024);
  attn_kernel<<<dim3(16, 32), 256, 0, stream>>>(qkv, lens, ao);
  gemm_kernel<1><<<dim3(8, 32), 256, 0, stream>>>(ao, wob, bo, nullptr, nullptr, nullptr, out, 1024);
}

// Round 8
// 201.902 us; speedup vs baseline: 1.1289x; 1.0485x over previous
//
#include <hip/hip_runtime.h>

// ---------------- common types / helpers ----------------
using bf16x8 = __attribute__((ext_vector_type(8))) short;
using f32x4  = __attribute__((ext_vector_type(4))) float;

#define S_LEN 2048
#define NHEAD 16
#define DKH   64
#define HSZ   (S_LEN * DKH * 32)  // B*H*S*DK = 4194304 elems per matrix
// 1/sqrt(64) * log2(e): softmax done in exp2 domain
#define QSCALE 0.18033688011112042f

#if __has_builtin(__builtin_amdgcn_exp2f)
#define EXP2(x) __builtin_amdgcn_exp2f(x)
#else
#define EXP2(x) exp2f(x)
#endif

__device__ __forceinline__ unsigned short f2bf(float x) {
  unsigned u = __builtin_bit_cast(unsigned, x);
  u += 0x7FFFu + ((u >> 16) & 1u);  // RNE
  return (unsigned short)(u >> 16);
}

__device__ __forceinline__ void gload_lds16(const void* g, void* l) {
  __builtin_amdgcn_global_load_lds(
      (const __attribute__((address_space(1))) unsigned int*)g,
      (__attribute__((address_space(3))) unsigned int*)l, 16, 0, 0);
}

// ---------------- fused fp32->bf16 conversion + prefix lengths ----------
__global__ void cvt_lens_kernel(const float* __restrict__ x,
                                const float* __restrict__ wq,
                                const float* __restrict__ wk,
                                const float* __restrict__ wv,
                                const float* __restrict__ wo,
                                const int* __restrict__ mask,
                                unsigned short* __restrict__ xb,
                                unsigned short* __restrict__ wb,
                                unsigned short* __restrict__ wob,
                                int* __restrict__ lens) {
  __shared__ int sred[256];
  if (blockIdx.x >= 8192) {
    // ---- lens for b = blockIdx.x - 8192 ----
    const int b = blockIdx.x - 8192;
    int c = 0;
    for (int s = threadIdx.x; s < S_LEN; s += 256) c += (mask[b * S_LEN + s] != 0) ? 1 : 0;
    sred[threadIdx.x] = c;
    __syncthreads();
    for (int st = 128; st > 0; st >>= 1) {
      if (threadIdx.x < st) sred[threadIdx.x] += sred[threadIdx.x + st];
      __syncthreads();
    }
    if (threadIdx.x == 0) lens[b] = sred[0];
    return;
  }
  const int i = blockIdx.x * 256 + threadIdx.x;  // float4-group index
  const float* s;
  unsigned short* d;
  if (i < 1048576) {
    s = x + (size_t)i * 4;            d = xb + (size_t)i * 4;
  } else if (i < 1310720) {
    const int j = i - 1048576;
    s = wq + (size_t)j * 4;           d = wb + (size_t)j * 4;
  } else if (i < 1572864) {
    const int j = i - 1310720;
    s = wk + (size_t)j * 4;           d = wb + 1048576 + (size_t)j * 4;
  } else if (i < 1835008) {
    const int j = i - 1572864;
    s = wv + (size_t)j * 4;           d = wb + 2097152 + (size_t)j * 4;
  } else {
    const int j = i - 1835008;
    s = wo + (size_t)j * 4;           d = wob + (size_t)j * 4;
  }
  float4 v = *(const float4*)s;
  ushort4 o;
  o.x = f2bf(v.x); o.y = f2bf(v.y); o.z = f2bf(v.z); o.w = f2bf(v.w);
  *(ushort4*)d = o;
}

// ---------------- 128x128x32 bf16 GEMM, dbuf + counted vmcnt (T4) -------
// C[m,n] = sum_k A[m,k]*B[n,k]  (A: MxK row-major, B: NxK row-major)
// K-loop: issue stage(t+1) early; wait vmcnt(4) (own tile-t loads only; the
// 4 tile-t+1 loads stay in flight ACROSS the barrier); raw s_barrier.
// Buffer-reuse hazard protected by lgkmcnt(0) + second raw barrier.
// MODE 0: QKV epilogue (R4-verified scalar): Q,K -> [B,H,S,DK] (Q*QSCALE),
//         V -> transposed [B,H,DK,S]. MODE 1: fp32 out + bias.
template <int MODE>
__global__ __launch_bounds__(256) void gemm_kernel(
    const unsigned short* __restrict__ A, const unsigned short* __restrict__ B,
    const float* __restrict__ b0, const float* __restrict__ b1,
    const float* __restrict__ b2, unsigned short* __restrict__ outQKV,
    float* __restrict__ outF, const int K) {
  __shared__ __align__(16) unsigned short As[2][128 * 32];
  __shared__ __align__(16) unsigned short Bs[2][128 * 32];
  const int tid = threadIdx.x;
  const int w = tid >> 6, lane = tid & 63;
  const int wm = w >> 1, wn = w & 1;
  const int r = lane & 15, g = lane >> 4;
  const int tm = blockIdx.y * 128, tn = blockIdx.x * 128;

  f32x4 acc[4][4] = {};
  const char* Ab = (const char*)A;
  const char* Bb = (const char*)B;
  const int nk = K >> 5;

  auto stage = [&](int kt, int bb) {
    char* ad = (char*)As[bb];
    char* bd = (char*)Bs[bb];
    const int k0 = kt * 32;
#pragma unroll
    for (int i = 0; i < 2; ++i) {
      const int o = (w * 2 + i) * 1024 + lane * 16;  // byte offset in 8KB tile
      const int row = o >> 6, colb = o & 63;
      gload_lds16(Ab + ((size_t)(tm + row) * K + k0) * 2 + colb, ad + (w * 2 + i) * 1024);
      gload_lds16(Bb + ((size_t)(tn + row) * K + k0) * 2 + colb, bd + (w * 2 + i) * 1024);
    }
  };

  stage(0, 0);
  int buf = 0;
  for (int kt = 0; kt < nk; ++kt) {
    if (kt + 1 < nk) {
      stage(kt + 1, buf ^ 1);  // 4 more loads -> 8 outstanding
      asm volatile("s_waitcnt vmcnt(4)" ::: "memory");  // tile-kt landed
    } else {
      asm volatile("s_waitcnt vmcnt(0)" ::: "memory");  // last tile: drain
    }
    __builtin_amdgcn_s_barrier();  // all waves' tile-kt quarters in LDS
    __builtin_amdgcn_sched_barrier(0);

    const char* AsB = (const char*)As[buf];
    const char* BsB = (const char*)Bs[buf];
    bf16x8 af[4], bfr[4];
#pragma unroll
    for (int mi = 0; mi < 4; ++mi)
      af[mi] = *(const bf16x8*)(AsB + (wm * 64 + mi * 16 + r) * 64 + g * 16);
#pragma unroll
    for (int ni = 0; ni < 4; ++ni)
      bfr[ni] = *(const bf16x8*)(BsB + (wn * 64 + ni * 16 + r) * 64 + g * 16);
#pragma unroll
    for (int mi = 0; mi < 4; ++mi)
#pragma unroll
      for (int ni = 0; ni < 4; ++ni)
        acc[mi][ni] = __builtin_amdgcn_mfma_f32_16x16x32_bf16(af[mi], bfr[ni], acc[mi][ni], 0, 0, 0);

    asm volatile("s_waitcnt lgkmcnt(0)" ::: "memory");  // ds_reads of buf done
    __builtin_amdgcn_sched_barrier(0);
    __builtin_amdgcn_s_barrier();  // safe to overwrite buf next iter
    buf ^= 1;
  }

  if (MODE == 0) {
    const int mat = tn >> 10;  // tile never straddles a 1024 boundary
    const float* bp = (mat == 0) ? b0 : (mat == 1) ? b1 : b2;
    const float scale = (mat == 0) ? QSCALE : 1.0f;
    unsigned short* dst = outQKV + (size_t)mat * HSZ;
#pragma unroll
    for (int mi = 0; mi < 4; ++mi)
#pragma unroll
      for (int ni = 0; ni < 4; ++ni)
#pragma unroll
        for (int reg = 0; reg < 4; ++reg) {
          const int m = tm + wm * 64 + mi * 16 + 4 * g + reg;
          const int n = tn + wn * 64 + ni * 16 + r;
          const int nn = n & 1023;
          const float v = (acc[mi][ni][reg] + bp[nn]) * scale;
          const int bI = m >> 11, s = m & 2047, hh = nn >> 6, dk = nn & 63;
          if (mat == 2) {
            // V^T: [B,H,DK,S]
            dst[(size_t)((bI * NHEAD + hh) * DKH + dk) * S_LEN + s] = f2bf(v);
          } else {
            dst[(size_t)((bI * NHEAD + hh) * S_LEN + s) * DKH + dk] = f2bf(v);
          }
        }
  } else {
#pragma unroll
    for (int mi = 0; mi < 4; ++mi)
#pragma unroll
      for (int ni = 0; ni < 4; ++ni)
#pragma unroll
        for (int reg = 0; reg < 4; ++reg) {
          const int m = tm + wm * 64 + mi * 16 + 4 * g + reg;
          const int n = tn + wn * 64 + ni * 16 + r;
          outF[(size_t)m * 1024 + n] = acc[mi][ni][reg] + b0[n];
        }
  }
}

// ---------------- online-softmax helper (exp2 domain, exact rescale) -----
__device__ __forceinline__ void online_sm(f32x4* st, float& mrun, float& lrun,
                                          f32x4* oacc, int g) {
  float mloc = st[0][0];
#pragma unroll
  for (int f = 0; f < 4; ++f)
#pragma unroll
    for (int q = 0; q < 4; ++q) mloc = fmaxf(mloc, st[f][q]);
  mloc = fmaxf(mloc, __shfl_xor(mloc, 16));
  mloc = fmaxf(mloc, __shfl_xor(mloc, 32));
  const float mnew = fmaxf(mrun, mloc);
  const float alpha = EXP2(mrun - mnew);  // first tile: exp2(-inf) = 0
  mrun = mnew;
  float psum = 0.f;
#pragma unroll
  for (int f = 0; f < 4; ++f)
#pragma unroll
    for (int q = 0; q < 4; ++q) {
      const float p = EXP2(st[f][q] - mnew);
      st[f][q] = p;
      psum += p;
    }
  psum += __shfl_xor(psum, 16);
  psum += __shfl_xor(psum, 32);
  lrun = lrun * alpha + psum;
  float areg[4];
#pragma unroll
  for (int q = 0; q < 4; ++q) areg[q] = __shfl(alpha, 4 * g + q);
#pragma unroll
  for (int f = 0; f < 4; ++f)
#pragma unroll
    for (int q = 0; q < 4; ++q) oacc[f][q] *= areg[q];
}

// ---------------- flash attention (unchanged from verified R4) ----------
// grid (S/128, B*H); 4 waves x 32 q-rows (2 groups of 16). Swapped QK^T.
// K and V^T double-buffered in LDS, both staged via global_load_lds with
// pre-swizzled global source (XOR (row&7)<<4). PV reads V^T rows directly.
__global__ __launch_bounds__(256) void attn_kernel(
    const unsigned short* __restrict__ qkv, const int* __restrict__ lens,
    unsigned short* __restrict__ outc) {
  __shared__ __align__(16) unsigned short Kt[2][4096];  // [buf][c][dk] swz
  __shared__ __align__(16) unsigned short Vt[2][4096];  // [buf][dk][c] swz (V^T)
  __shared__ __align__(16) unsigned short Pl[4][2][1024];  // [wave][grp][q][c] swz
  const int tid = threadIdx.x;
  const int w = tid >> 6, lane = tid & 63;
  const int r = lane & 15, g = lane >> 4;
  const int bh = blockIdx.y;
  const int b = bh >> 4, h = bh & 15;
  const int q0 = blockIdx.x * 128;

  const unsigned short* Qp = qkv;
  const unsigned short* Kp = qkv + HSZ;
  const unsigned short* VTp = qkv + 2 * (size_t)HSZ;  // [B,H,DK,S]

  const size_t qbase = (size_t)(bh * S_LEN + q0 + w * 32 + r) * DKH;
  const bf16x8 qa0 = *(const bf16x8*)(Qp + qbase + g * 8);
  const bf16x8 qa1 = *(const bf16x8*)(Qp + qbase + 32 + g * 8);
  const bf16x8 qb0 = *(const bf16x8*)(Qp + qbase + 16 * DKH + g * 8);
  const bf16x8 qb1 = *(const bf16x8*)(Qp + qbase + 16 * DKH + 32 + g * 8);

  const int L = lens[b];
  const int nt = (L + 63) >> 6;
  float mA = -__builtin_inff(), lA = 0.f;
  float mB = -__builtin_inff(), lB = 0.f;
  f32x4 oA[4] = {}, oB[4] = {};

  char* PA = (char*)Pl[w][0];
  char* PB = (char*)Pl[w][1];
  const int swp = (r & 7) << 4;

  const char* kgb0 = (const char*)(Kp + (size_t)bh * S_LEN * DKH);
  const char* vgb0 = (const char*)(VTp + (size_t)bh * DKH * S_LEN);

  auto stage = [&](int tt, int bb) {
    const char* kgb = kgb0 + (size_t)tt * 64 * DKH * 2;  // K tile base
    const char* vgb = vgb0 + (size_t)tt * 64 * 2;        // V^T col offset
    char* kd = (char*)Kt[bb];
    char* vd = (char*)Vt[bb];
#pragma unroll
    for (int i = 0; i < 2; ++i) {
      const int o = i * 4096 + w * 1024 + lane * 16;
      const int row = o >> 7, colb = o & 127;
      const int cs = colb ^ ((row & 7) << 4);
      gload_lds16(kgb + row * 128 + cs, kd + i * 4096 + w * 1024);
      gload_lds16(vgb + (size_t)row * (S_LEN * 2) + cs, vd + i * 4096 + w * 1024);
    }
  };

  if (nt > 0) stage(0, 0);
  __syncthreads();

  int buf = 0;
  for (int t = 0; t < nt; ++t) {
    if (t + 1 < nt) stage(t + 1, buf ^ 1);  // issue early, drains at end barrier

    const char* KtB = (const char*)Kt[buf];
    f32x4 sa[4], sb[4];
    __builtin_amdgcn_s_setprio(1);
#pragma unroll
    for (int f = 0; f < 4; ++f) {
      const int c = f * 16 + r;
      const int sw = (c & 7) << 4;
      const bf16x8 k0 = *(const bf16x8*)(KtB + c * 128 + ((g * 16) ^ sw));
      const bf16x8 k1 = *(const bf16x8*)(KtB + c * 128 + ((64 + g * 16) ^ sw));
      f32x4 x = {};
      x = __builtin_amdgcn_mfma_f32_16x16x32_bf16(k0, qa0, x, 0, 0, 0);
      x = __builtin_amdgcn_mfma_f32_16x16x32_bf16(k1, qa1, x, 0, 0, 0);
      sa[f] = x;
      f32x4 y = {};
      y = __builtin_amdgcn_mfma_f32_16x16x32_bf16(k0, qb0, y, 0, 0, 0);
      y = __builtin_amdgcn_mfma_f32_16x16x32_bf16(k1, qb1, y, 0, 0, 0);
      sb[f] = y;
    }
    __builtin_amdgcn_s_setprio(0);

    const int kv0 = t * 64;
    if (t == nt - 1) {
#pragma unroll
      for (int f = 0; f < 4; ++f)
#pragma unroll
        for (int q = 0; q < 4; ++q)
          if (kv0 + f * 16 + 4 * g + q >= L) {
            sa[f][q] = -__builtin_inff();
            sb[f][q] = -__builtin_inff();
          }
    }

    online_sm(sa, mA, lA, oA, g);
    online_sm(sb, mB, lB, oB, g);

#pragma unroll
    for (int f = 0; f < 4; ++f) {
      ushort4 pw;
      pw.x = f2bf(sa[f][0]); pw.y = f2bf(sa[f][1]);
      pw.z = f2bf(sa[f][2]); pw.w = f2bf(sa[f][3]);
      *(ushort4*)(PA + r * 128 + ((f * 32 + g * 8) ^ swp)) = pw;
      ushort4 qw;
      qw.x = f2bf(sb[f][0]); qw.y = f2bf(sb[f][1]);
      qw.z = f2bf(sb[f][2]); qw.w = f2bf(sb[f][3]);
      *(ushort4*)(PB + r * 128 + ((f * 32 + g * 8) ^ swp)) = qw;
    }

    const char* VtB = (const char*)Vt[buf];
#pragma unroll
    for (int c2 = 0; c2 < 2; ++c2) {
      const bf16x8 pa = *(const bf16x8*)(PA + r * 128 + ((c2 * 64 + g * 16) ^ swp));
      const bf16x8 pb = *(const bf16x8*)(PB + r * 128 + ((c2 * 64 + g * 16) ^ swp));
      __builtin_amdgcn_s_setprio(1);
#pragma unroll
      for (int f = 0; f < 4; ++f) {
        const int dk = f * 16 + r;
        const bf16x8 vf =
            *(const bf16x8*)(VtB + dk * 128 + ((c2 * 64 + g * 16) ^ ((dk & 7) << 4)));
        oA[f] = __builtin_amdgcn_mfma_f32_16x16x32_bf16(pa, vf, oA[f], 0, 0, 0);
        oB[f] = __builtin_amdgcn_mfma_f32_16x16x32_bf16(pb, vf, oB[f], 0, 0, 0);
      }
      __builtin_amdgcn_s_setprio(0);
    }

    __syncthreads();  // drains t+1 staging (vmcnt) + protects buf reuse
    buf ^= 1;
  }

  const float iA = 1.0f / lA;
  const float iB = 1.0f / lB;
  float rA[4], rB[4];
#pragma unroll
  for (int q = 0; q < 4; ++q) {
    rA[q] = __shfl(iA, 4 * g + q);
    rB[q] = __shfl(iB, 4 * g + q);
  }
#pragma unroll
  for (int f = 0; f < 4; ++f) {
    const int dk = f * 16 + r;
#pragma unroll
    for (int q = 0; q < 4; ++q) {
      const int rowA = q0 + w * 32 + 4 * g + q;
      outc[(size_t)(b * S_LEN + rowA) * 1024 + h * DKH + dk] = f2bf(oA[f][q] * rA[q]);
      const int rowB = rowA + 16;
      outc[(size_t)(b * S_LEN + rowB) * 1024 + h * DKH + dk] = f2bf(oB[f][q] * rB[q]);
    }
  }
}

// ---------------- launch ----------------
extern "C" void kernel_launch(void* const* d_in, const int* in_sizes, int n_in,
                              void* d_out, int out_size, void* d_ws, size_t ws_size,
                              hipStream_t stream) {
  const float* x  = (const float*)d_in[0];
  const int* mask = (const int*)d_in[1];
  const float* wq = (const float*)d_in[2];
  const float* bq = (const float*)d_in[3];
  const float* wk = (const float*)d_in[4];
  const float* bk = (const float*)d_in[5];
  const float* wv = (const float*)d_in[6];
  const float* bv = (const float*)d_in[7];
  const float* wo = (const float*)d_in[8];
  const float* bo = (const float*)d_in[9];
  (void)in_sizes; (void)n_in; (void)out_size; (void)ws_size;

  char* ws = (char*)d_ws;
  unsigned short* xb  = (unsigned short*)ws;                  // 4M elems (8 MB)
  unsigned short* wb  = (unsigned short*)(ws + 8388608);      // 3M elems (Wq|Wk|Wv)
  unsigned short* wob = (unsigned short*)(ws + 14680064);     // 1M elems
  unsigned short* qkv = (unsigned short*)(ws + 16777216);     // Q|K|V^T, 3 x 4M elems
  unsigned short* ao  = (unsigned short*)(ws + 41943040);     // 4M elems
  int* lens           = (int*)(ws + 50331648);
  float* out          = (float*)d_out;

  cvt_lens_kernel<<<8194, 256, 0, stream>>>(x, wq, wk, wv, wo, mask, xb, wb, wob, lens);

  gemm_kernel<0><<<dim3(24, 32), 256, 0, stream>>>(xb, wb, bq, bk, bv, qkv, nullptr, 1024);
  attn_kernel<<<dim3(16, 32), 256, 0, stream>>>(qkv, lens, ao);
  gemm_kernel<1><<<dim3(8, 32), 256, 0, stream>>>(ao, wob, bo, nullptr, nullptr, nullptr, out, 1024);
}

// Round 11
// 197.362 us; speedup vs baseline: 1.1549x; 1.0230x over previous
//
#include <hip/hip_runtime.h>

// ---------------- common types / helpers ----------------
using bf16x8 = __attribute__((ext_vector_type(8))) short;
using f32x4  = __attribute__((ext_vector_type(4))) float;

#define S_LEN 2048
#define NHEAD 16
#define DKH   64
#define HSZ   (S_LEN * DKH * 32)  // B*H*S*DK = 4194304 elems per matrix
// 1/sqrt(64) * log2(e): softmax done in exp2 domain
#define QSCALE 0.18033688011112042f

#if __has_builtin(__builtin_amdgcn_exp2f)
#define EXP2(x) __builtin_amdgcn_exp2f(x)
#else
#define EXP2(x) exp2f(x)
#endif

__device__ __forceinline__ unsigned short f2bf(float x) {
  unsigned u = __builtin_bit_cast(unsigned, x);
  u += 0x7FFFu + ((u >> 16) & 1u);  // RNE
  return (unsigned short)(u >> 16);
}

// pack 2 fp32 -> 2 bf16 in one VALU op (no builtin on gfx950; T12 recipe)
__device__ __forceinline__ unsigned cvt_pk_bf16(float lo, float hi) {
  unsigned r;
  asm("v_cvt_pk_bf16_f32 %0, %1, %2" : "=v"(r) : "v"(lo), "v"(hi));
  return r;
}

__device__ __forceinline__ void gload_lds16(const void* g, void* l) {
  __builtin_amdgcn_global_load_lds(
      (const __attribute__((address_space(1))) unsigned int*)g,
      (__attribute__((address_space(3))) unsigned int*)l, 16, 0, 0);
}

// ---------------- fused fp32->bf16 conversion + prefix lengths ----------
__global__ void cvt_lens_kernel(const float* __restrict__ x,
                                const float* __restrict__ wq,
                                const float* __restrict__ wk,
                                const float* __restrict__ wv,
                                const float* __restrict__ wo,
                                const int* __restrict__ mask,
                                unsigned short* __restrict__ xb,
                                unsigned short* __restrict__ wb,
                                unsigned short* __restrict__ wob,
                                int* __restrict__ lens) {
  __shared__ int sred[256];
  if (blockIdx.x >= 8192) {
    // ---- lens for b = blockIdx.x - 8192 ----
    const int b = blockIdx.x - 8192;
    int c = 0;
    for (int s = threadIdx.x; s < S_LEN; s += 256) c += (mask[b * S_LEN + s] != 0) ? 1 : 0;
    sred[threadIdx.x] = c;
    __syncthreads();
    for (int st = 128; st > 0; st >>= 1) {
      if (threadIdx.x < st) sred[threadIdx.x] += sred[threadIdx.x + st];
      __syncthreads();
    }
    if (threadIdx.x == 0) lens[b] = sred[0];
    return;
  }
  const int i = blockIdx.x * 256 + threadIdx.x;  // float4-group index
  const float* s;
  unsigned short* d;
  if (i < 1048576) {
    s = x + (size_t)i * 4;            d = xb + (size_t)i * 4;
  } else if (i < 1310720) {
    const int j = i - 1048576;
    s = wq + (size_t)j * 4;           d = wb + (size_t)j * 4;
  } else if (i < 1572864) {
    const int j = i - 1310720;
    s = wk + (size_t)j * 4;           d = wb + 1048576 + (size_t)j * 4;
  } else if (i < 1835008) {
    const int j = i - 1572864;
    s = wv + (size_t)j * 4;           d = wb + 2097152 + (size_t)j * 4;
  } else {
    const int j = i - 1835008;
    s = wo + (size_t)j * 4;           d = wob + (size_t)j * 4;
  }
  float4 v = *(const float4*)s;
  ushort4 o;
  o.x = f2bf(v.x); o.y = f2bf(v.y); o.z = f2bf(v.z); o.w = f2bf(v.w);
  *(ushort4*)d = o;
}

// ---------------- 128x128x32 bf16 GEMM, dbuf + counted vmcnt (T4) -------
// C[m,n] = sum_k A[m,k]*B[n,k]  (A: MxK row-major, B: NxK row-major)
// K-loop: issue stage(t+1) early; wait vmcnt(4) (own tile-t loads only; the
// 4 tile-t+1 loads stay in flight ACROSS the barrier); raw s_barrier.
// All output tiles always computed (no lens early-out: every d_ws byte the
// pipeline reads is written in the SAME call — replay-state independent).
// MODE 0: QKV epilogue: Q,K -> [B,H,S,DK] (Q*QSCALE), V -> [B,H,DK,S].
// MODE 1: fp32 out + bias.
template <int MODE>
__global__ __launch_bounds__(256) void gemm_kernel(
    const unsigned short* __restrict__ A, const unsigned short* __restrict__ B,
    const float* __restrict__ b0, const float* __restrict__ b1,
    const float* __restrict__ b2, unsigned short* __restrict__ outQKV,
    float* __restrict__ outF, const int K) {
  __shared__ __align__(16) unsigned short As[2][128 * 32];
  __shared__ __align__(16) unsigned short Bs[2][128 * 32];
  const int tid = threadIdx.x;
  const int w = tid >> 6, lane = tid & 63;
  const int wm = w >> 1, wn = w & 1;
  const int r = lane & 15, g = lane >> 4;
  const int tm = blockIdx.y * 128, tn = blockIdx.x * 128;

  f32x4 acc[4][4] = {};
  const char* Ab = (const char*)A;
  const char* Bb = (const char*)B;
  const int nk = K >> 5;

  auto stage = [&](int kt, int bb) {
    char* ad = (char*)As[bb];
    char* bd = (char*)Bs[bb];
    const int k0 = kt * 32;
#pragma unroll
    for (int i = 0; i < 2; ++i) {
      const int o = (w * 2 + i) * 1024 + lane * 16;  // byte offset in 8KB tile
      const int row = o >> 6, colb = o & 63;
      gload_lds16(Ab + ((size_t)(tm + row) * K + k0) * 2 + colb, ad + (w * 2 + i) * 1024);
      gload_lds16(Bb + ((size_t)(tn + row) * K + k0) * 2 + colb, bd + (w * 2 + i) * 1024);
    }
  };

  stage(0, 0);
  int buf = 0;
  for (int kt = 0; kt < nk; ++kt) {
    if (kt + 1 < nk) {
      stage(kt + 1, buf ^ 1);  // 4 more loads -> 8 outstanding
      asm volatile("s_waitcnt vmcnt(4)" ::: "memory");  // tile-kt landed
    } else {
      asm volatile("s_waitcnt vmcnt(0)" ::: "memory");  // last tile: drain
    }
    __builtin_amdgcn_s_barrier();  // all waves' tile-kt quarters in LDS
    __builtin_amdgcn_sched_barrier(0);

    const char* AsB = (const char*)As[buf];
    const char* BsB = (const char*)Bs[buf];
    bf16x8 af[4], bfr[4];
#pragma unroll
    for (int mi = 0; mi < 4; ++mi)
      af[mi] = *(const bf16x8*)(AsB + (wm * 64 + mi * 16 + r) * 64 + g * 16);
#pragma unroll
    for (int ni = 0; ni < 4; ++ni)
      bfr[ni] = *(const bf16x8*)(BsB + (wn * 64 + ni * 16 + r) * 64 + g * 16);
#pragma unroll
    for (int mi = 0; mi < 4; ++mi)
#pragma unroll
      for (int ni = 0; ni < 4; ++ni)
        acc[mi][ni] = __builtin_amdgcn_mfma_f32_16x16x32_bf16(af[mi], bfr[ni], acc[mi][ni], 0, 0, 0);

    asm volatile("s_waitcnt lgkmcnt(0)" ::: "memory");  // ds_reads of buf done
    __builtin_amdgcn_sched_barrier(0);
    __builtin_amdgcn_s_barrier();  // safe to overwrite buf next iter
    buf ^= 1;
  }

  if (MODE == 0) {
    const int mat = tn >> 10;  // tile never straddles a 1024 boundary
    const float* bp = (mat == 0) ? b0 : (mat == 1) ? b1 : b2;
    const float scale = (mat == 0) ? QSCALE : 1.0f;
    unsigned short* dst = outQKV + (size_t)mat * HSZ;
#pragma unroll
    for (int mi = 0; mi < 4; ++mi)
#pragma unroll
      for (int ni = 0; ni < 4; ++ni)
#pragma unroll
        for (int reg = 0; reg < 4; ++reg) {
          const int m = tm + wm * 64 + mi * 16 + 4 * g + reg;
          const int n = tn + wn * 64 + ni * 16 + r;
          const int nn = n & 1023;
          const float v = (acc[mi][ni][reg] + bp[nn]) * scale;
          const int bI = m >> 11, s = m & 2047, hh = nn >> 6, dk = nn & 63;
          if (mat == 2) {
            // V^T: [B,H,DK,S]
            dst[(size_t)((bI * NHEAD + hh) * DKH + dk) * S_LEN + s] = f2bf(v);
          } else {
            dst[(size_t)((bI * NHEAD + hh) * S_LEN + s) * DKH + dk] = f2bf(v);
          }
        }
  } else {
#pragma unroll
    for (int mi = 0; mi < 4; ++mi)
#pragma unroll
      for (int ni = 0; ni < 4; ++ni)
#pragma unroll
        for (int reg = 0; reg < 4; ++reg) {
          const int m = tm + wm * 64 + mi * 16 + 4 * g + reg;
          const int n = tn + wn * 64 + ni * 16 + r;
          outF[(size_t)m * 1024 + n] = acc[mi][ni][reg] + b0[n];
        }
  }
}

// ------- online-softmax (exp2 domain, defer-max THR=8 -> P <= 2^8) ------
__device__ __forceinline__ void online_sm(f32x4* st, float& mrun, float& lrun,
                                          f32x4* oacc, int g) {
  float mloc = st[0][0];
#pragma unroll
  for (int f = 0; f < 4; ++f)
#pragma unroll
    for (int q = 0; q < 4; ++q) mloc = fmaxf(mloc, st[f][q]);
  mloc = fmaxf(mloc, __shfl_xor(mloc, 16));
  mloc = fmaxf(mloc, __shfl_xor(mloc, 32));
  if (!__all(mloc - mrun <= 8.0f)) {  // rescale only when max grew > THR
    const float mnew = fmaxf(mrun, mloc);
    const float alpha = EXP2(mrun - mnew);  // first tile: exp2(-inf) = 0
    float areg[4];
#pragma unroll
    for (int q = 0; q < 4; ++q) areg[q] = __shfl(alpha, 4 * g + q);
#pragma unroll
    for (int f = 0; f < 4; ++f)
#pragma unroll
      for (int q = 0; q < 4; ++q) oacc[f][q] *= areg[q];
    lrun *= alpha;
    mrun = mnew;
  }
  float psum = 0.f;
#pragma unroll
  for (int f = 0; f < 4; ++f)
#pragma unroll
    for (int q = 0; q < 4; ++q) {
      const float p = EXP2(st[f][q] - mrun);
      st[f][q] = p;
      psum += p;
    }
  psum += __shfl_xor(psum, 16);
  psum += __shfl_xor(psum, 32);
  lrun += psum;
}

// ---------------- flash attention ----------------
// grid (S/128, B*H); 4 waves x 32 q-rows (2 groups of 16). Swapped QK^T.
// K and V^T double-buffered in LDS, both staged via global_load_lds with
// pre-swizzled global source (XOR (row&7)<<4). PV reads V^T rows directly.
__global__ __launch_bounds__(256) void attn_kernel(
    const unsigned short* __restrict__ qkv, const int* __restrict__ lens,
    unsigned short* __restrict__ outc) {
  __shared__ __align__(16) unsigned short Kt[2][4096];  // [buf][c][dk] swz
  __shared__ __align__(16) unsigned short Vt[2][4096];  // [buf][dk][c] swz (V^T)
  __shared__ __align__(16) unsigned short Pl[4][2][1024];  // [wave][grp][q][c] swz
  const int tid = threadIdx.x;
  const int w = tid >> 6, lane = tid & 63;
  const int r = lane & 15, g = lane >> 4;
  const int bh = blockIdx.y;
  const int b = bh >> 4, h = bh & 15;
  const int q0 = blockIdx.x * 128;

  const unsigned short* Qp = qkv;
  const unsigned short* Kp = qkv + HSZ;
  const unsigned short* VTp = qkv + 2 * (size_t)HSZ;  // [B,H,DK,S]

  const size_t qbase = (size_t)(bh * S_LEN + q0 + w * 32 + r) * DKH;
  const bf16x8 qa0 = *(const bf16x8*)(Qp + qbase + g * 8);
  const bf16x8 qa1 = *(const bf16x8*)(Qp + qbase + 32 + g * 8);
  const bf16x8 qb0 = *(const bf16x8*)(Qp + qbase + 16 * DKH + g * 8);
  const bf16x8 qb1 = *(const bf16x8*)(Qp + qbase + 16 * DKH + 32 + g * 8);

  const int L = lens[b];
  const int nt = (L + 63) >> 6;
  float mA = -__builtin_inff(), lA = 0.f;
  float mB = -__builtin_inff(), lB = 0.f;
  f32x4 oA[4] = {}, oB[4] = {};

  char* PA = (char*)Pl[w][0];
  char* PB = (char*)Pl[w][1];
  const int swp = (r & 7) << 4;

  const char* kgb0 = (const char*)(Kp + (size_t)bh * S_LEN * DKH);
  const char* vgb0 = (const char*)(VTp + (size_t)bh * DKH * S_LEN);

  auto stage = [&](int tt, int bb) {
    const char* kgb = kgb0 + (size_t)tt * 64 * DKH * 2;  // K tile base
    const char* vgb = vgb0 + (size_t)tt * 64 * 2;        // V^T col offset
    char* kd = (char*)Kt[bb];
    char* vd = (char*)Vt[bb];
#pragma unroll
    for (int i = 0; i < 2; ++i) {
      const int o = i * 4096 + w * 1024 + lane * 16;
      const int row = o >> 7, colb = o & 127;
      const int cs = colb ^ ((row & 7) << 4);
      gload_lds16(kgb + row * 128 + cs, kd + i * 4096 + w * 1024);
      gload_lds16(vgb + (size_t)row * (S_LEN * 2) + cs, vd + i * 4096 + w * 1024);
    }
  };

  if (nt > 0) stage(0, 0);
  __syncthreads();

  int buf = 0;
  for (int t = 0; t < nt; ++t) {
    if (t + 1 < nt) stage(t + 1, buf ^ 1);  // issue early, drains at end barrier

    const char* KtB = (const char*)Kt[buf];
    f32x4 sa[4], sb[4];
    __builtin_amdgcn_s_setprio(1);
#pragma unroll
    for (int f = 0; f < 4; ++f) {
      const int c = f * 16 + r;
      const int sw = (c & 7) << 4;
      const bf16x8 k0 = *(const bf16x8*)(KtB + c * 128 + ((g * 16) ^ sw));
      const bf16x8 k1 = *(const bf16x8*)(KtB + c * 128 + ((64 + g * 16) ^ sw));
      f32x4 x = {};
      x = __builtin_amdgcn_mfma_f32_16x16x32_bf16(k0, qa0, x, 0, 0, 0);
      x = __builtin_amdgcn_mfma_f32_16x16x32_bf16(k1, qa1, x, 0, 0, 0);
      sa[f] = x;
      f32x4 y = {};
      y = __builtin_amdgcn_mfma_f32_16x16x32_bf16(k0, qb0, y, 0, 0, 0);
      y = __builtin_amdgcn_mfma_f32_16x16x32_bf16(k1, qb1, y, 0, 0, 0);
      sb[f] = y;
    }
    __builtin_amdgcn_s_setprio(0);

    const int kv0 = t * 64;
    if (t == nt - 1) {
#pragma unroll
      for (int f = 0; f < 4; ++f)
#pragma unroll
        for (int q = 0; q < 4; ++q)
          if (kv0 + f * 16 + 4 * g + q >= L) {
            sa[f][q] = -__builtin_inff();
            sb[f][q] = -__builtin_inff();
          }
    }

    online_sm(sa, mA, lA, oA, g);
    online_sm(sb, mB, lB, oB, g);

    // ---- P -> LDS (bf16 via v_cvt_pk, swizzled, per-wave private) ----
#pragma unroll
    for (int f = 0; f < 4; ++f) {
      uint2 pw;
      pw.x = cvt_pk_bf16(sa[f][0], sa[f][1]);
      pw.y = cvt_pk_bf16(sa[f][2], sa[f][3]);
      *(uint2*)(PA + r * 128 + ((f * 32 + g * 8) ^ swp)) = pw;
      uint2 qw;
      qw.x = cvt_pk_bf16(sb[f][0], sb[f][1]);
      qw.y = cvt_pk_bf16(sb[f][2], sb[f][3]);
      *(uint2*)(PB + r * 128 + ((f * 32 + g * 8) ^ swp)) = qw;
    }

    const char* VtB = (const char*)Vt[buf];
#pragma unroll
    for (int c2 = 0; c2 < 2; ++c2) {
      const bf16x8 pa = *(const bf16x8*)(PA + r * 128 + ((c2 * 64 + g * 16) ^ swp));
      const bf16x8 pb = *(const bf16x8*)(PB + r * 128 + ((c2 * 64 + g * 16) ^ swp));
      __builtin_amdgcn_s_setprio(1);
#pragma unroll
      for (int f = 0; f < 4; ++f) {
        const int dk = f * 16 + r;
        const bf16x8 vf =
            *(const bf16x8*)(VtB + dk * 128 + ((c2 * 64 + g * 16) ^ ((dk & 7) << 4)));
        oA[f] = __builtin_amdgcn_mfma_f32_16x16x32_bf16(pa, vf, oA[f], 0, 0, 0);
        oB[f] = __builtin_amdgcn_mfma_f32_16x16x32_bf16(pb, vf, oB[f], 0, 0, 0);
      }
      __builtin_amdgcn_s_setprio(0);
    }

    __syncthreads();  // drains t+1 staging (vmcnt) + protects buf reuse
    buf ^= 1;
  }

  const float iA = 1.0f / lA;
  const float iB = 1.0f / lB;
  float rA[4], rB[4];
#pragma unroll
  for (int q = 0; q < 4; ++q) {
    rA[q] = __shfl(iA, 4 * g + q);
    rB[q] = __shfl(iB, 4 * g + q);
  }
#pragma unroll
  for (int f = 0; f < 4; ++f) {
    const int dk = f * 16 + r;
#pragma unroll
    for (int q = 0; q < 4; ++q) {
      const int rowA = q0 + w * 32 + 4 * g + q;
      outc[(size_t)(b * S_LEN + rowA) * 1024 + h * DKH + dk] = f2bf(oA[f][q] * rA[q]);
      const int rowB = rowA + 16;
      outc[(size_t)(b * S_LEN + rowB) * 1024 + h * DKH + dk] = f2bf(oB[f][q] * rB[q]);
    }
  }
}

// ---------------- launch ----------------
extern "C" void kernel_launch(void* const* d_in, const int* in_sizes, int n_in,
                              void* d_out, int out_size, void* d_ws, size_t ws_size,
                              hipStream_t stream) {
  const float* x  = (const float*)d_in[0];
  const int* mask = (const int*)d_in[1];
  const float* wq = (const float*)d_in[2];
  const float* bq = (const float*)d_in[3];
  const float* wk = (const float*)d_in[4];
  const float* bk = (const float*)d_in[5];
  const float* wv = (const float*)d_in[6];
  const float* bv = (const float*)d_in[7];
  const float* wo = (const float*)d_in[8];
  const float* bo = (const float*)d_in[9];
  (void)in_sizes; (void)n_in; (void)out_size; (void)ws_size;

  char* ws = (char*)d_ws;
  unsigned short* xb  = (unsigned short*)ws;                  // 4M elems (8 MB)
  unsigned short* wb  = (unsigned short*)(ws + 8388608);      // 3M elems (Wq|Wk|Wv)
  unsigned short* wob = (unsigned short*)(ws + 14680064);     // 1M elems
  unsigned short* qkv = (unsigned short*)(ws + 16777216);     // Q|K|V^T, 3 x 4M elems
  unsigned short* ao  = (unsigned short*)(ws + 41943040);     // 4M elems
  int* lens           = (int*)(ws + 50331648);
  float* out          = (float*)d_out;

  cvt_lens_kernel<<<8194, 256, 0, stream>>>(x, wq, wk, wv, wo, mask, xb, wb, wob, lens);

  gemm_kernel<0><<<dim3(24, 32), 256, 0, stream>>>(xb, wb, bq, bk, bv, qkv, nullptr, 1024);
  attn_kernel<<<dim3(16, 32), 256, 0, stream>>>(qkv, lens, ao);
  gemm_kernel<1><<<dim3(8, 32), 256, 0, stream>>>(ao, wob, bo, nullptr, nullptr, nullptr, out, 1024);
}